// Round 7
// baseline (281.730 us; speedup 1.0000x reference)
//
#include <hip/hip_runtime.h>
#include <hip/hip_bf16.h>

// BertSelfAttention (no mask). B=4, S=2048, H=1024, NH=16, HD=64. fp32 I/O.
// Round 13: qkv_gemm = 128x256 tile, 8 waves, 4 fine phases/K-tile with
// counted vmcnt(2) (T3+T4) + r11's LDS-bounce full-line epilogue. Grid
// (64,4,3)=768 = exactly 3 blocks/CU. attn reverted to r7 (best measured,
// 82.7us: 512-thr, 32 q/wave, double-buffer + __syncthreads). conv unchanged.
#define BB  4
#define SS  2048
#define HH  1024
#define NHH 16
#define HDD 64

typedef unsigned short u16;
typedef unsigned int   u32;
using bf16x8 = __attribute__((ext_vector_type(8))) short;   // 8 bf16 = 4 VGPRs
using f32x4  = __attribute__((ext_vector_type(4))) float;   // MFMA C/D 16x16
using f32x16 = __attribute__((ext_vector_type(16))) float;  // MFMA C/D 32x32
using u32x4  = __attribute__((ext_vector_type(4))) u32;

#define SBAR()   asm volatile("s_barrier" ::: "memory")
#define WAITV0() asm volatile("s_waitcnt vmcnt(0)" ::: "memory")
#define WAITV2() asm volatile("s_waitcnt vmcnt(2)" ::: "memory")
#define LGKM0()  asm volatile("s_waitcnt lgkmcnt(0)" ::: "memory")
#define SCHEDB() __builtin_amdgcn_sched_barrier(0)

// fp32 -> bf16 RNE.
__device__ __forceinline__ u16 f2b(float f) {
    union { float f; u32 u; } x; x.f = f;
    return (u16)((x.u + 0x7fffu + ((x.u >> 16) & 1u)) >> 16);
}

// async 16B global -> LDS (dest = wave-uniform base + lane*16).
__device__ __forceinline__ void gload16(const u16* g, u16* l) {
    __builtin_amdgcn_global_load_lds(
        (const __attribute__((address_space(1))) void*)g,
        (__attribute__((address_space(3))) void*)l, 16, 0, 0);
}

// ---------------------------------------------------------------------------
// conv: fused input conversion.
//   blocks [0,4096):      X fp32 -> bf16 straight copy (8 elems/thread)
//   blocks [4096,7168):   W[k][n] fp32 -> Wt[n][k] bf16 (32x32 transpose)
// ---------------------------------------------------------------------------
__global__ __launch_bounds__(256) void conv(
    const float* __restrict__ X,
    const float* __restrict__ Wq, const float* __restrict__ Wk,
    const float* __restrict__ Wv,
    u16* __restrict__ Xb, u16* __restrict__ Wt)
{
    const int bid = blockIdx.x;
    const int t = threadIdx.x;
    if (bid < 4096) {
        const int i = bid * 256 + t;
        float4 a = ((const float4*)X)[i * 2];
        float4 b = ((const float4*)X)[i * 2 + 1];
        ushort4 s0, s1;
        s0.x = f2b(a.x); s0.y = f2b(a.y); s0.z = f2b(a.z); s0.w = f2b(a.w);
        s1.x = f2b(b.x); s1.y = f2b(b.y); s1.z = f2b(b.z); s1.w = f2b(b.w);
        ((ushort4*)Xb)[i * 2] = s0;
        ((ushort4*)Xb)[i * 2 + 1] = s1;
        return;
    }
    const int idx = bid - 4096;
    const int z = idx >> 10, rem = idx & 1023;
    const int k0 = (rem >> 5) * 32, n0 = (rem & 31) * 32;
    const float* W = (z == 0) ? Wq : (z == 1) ? Wk : Wv;
    u16* out = Wt + (size_t)z * HH * HH;
    __shared__ float T[32][33];
    {
        const int kl = t >> 3, n4 = (t & 7) * 4;
        float4 v = *(const float4*)&W[(size_t)(k0 + kl) * HH + n0 + n4];
        T[n4 + 0][kl] = v.x; T[n4 + 1][kl] = v.y;
        T[n4 + 2][kl] = v.z; T[n4 + 3][kl] = v.w;
    }
    __syncthreads();
    {
        const int nl = t >> 3, k4 = (t & 7) * 4;
        ushort4 s;
        s.x = f2b(T[nl][k4 + 0]); s.y = f2b(T[nl][k4 + 1]);
        s.z = f2b(T[nl][k4 + 2]); s.w = f2b(T[nl][k4 + 3]);
        *(ushort4*)&out[(size_t)(n0 + nl) * HH + k0 + k4] = s;
    }
}

// ---------------------------------------------------------------------------
// qkv_gemm: 128m x 256n tile, BK=64, 512 threads = 8 waves (2m x 4n),
// per-wave 64x64 output (4x4 16x16x32 MFMA frags). LDS 96KB: dbuf
// A[128x64] + B[256x64] bf16, XOR-swizzled, global_load_lds.
// 4 fine phases per K-tile: (kc, n-half) quadrants, each
// { stage quota | [P1: vmcnt(2)] | SBAR | ds_read | lgkmcnt(0) | 8 MFMA |
//   SBAR }. Per-wave staging = 6 gloads/K-tile (A:2, B:4) spread 2/2/1/1;
// prefetch never drains to 0 in-loop. Grid (64,4,3) = 768 = 3 blocks/CU.
// Epilogue: r11 LDS-bounce (wave-private 8KB in Bs) -> full-128B-line stores.
// z<2 (Q,K): operands SWAPPED -> acc = D^T (regs step d) -> [b,h,s,d] rows.
//            Q pre-scaled by 0.125*log2(e).
// z=2 (V):   normal order -> V^T [b,h,d,s] rows.
// ---------------------------------------------------------------------------
__global__ __launch_bounds__(512, 2) void qkv_gemm(
    const u16* __restrict__ Xb, const u16* __restrict__ Wtb,
    const float* __restrict__ bq, const float* __restrict__ bk,
    const float* __restrict__ bv,
    u16* __restrict__ Qw, u16* __restrict__ Kw, u16* __restrict__ Vw)
{
    const int z  = blockIdx.z;
    const float* bias = (z == 0) ? bq : (z == 1) ? bk : bv;
    const int m0 = blockIdx.x * 128, n0 = blockIdx.y * 256;

    __shared__ __align__(16) u16 As[2][128 * 64];   // 32 KB
    __shared__ __align__(16) u16 Bs[2][256 * 64];   // 64 KB

    const int t = threadIdx.x;
    const int w = t >> 6, lane = t & 63, lr = lane & 15, quad = lane >> 4;
    const int l3 = lane >> 3, c7 = lane & 7;
    const int cl = (c7 ^ l3) * 8;          // swizzled source column (u16)
    const int wm = w >> 2, wn = w & 3;     // 2m x 4n wave grid

    const u16* Wtz = Wtb + (size_t)z * HH * HH;

    // per-wave staging units: A rows w*16..w*16+15 (2 gloads),
    // B rows w*32..w*32+31 (4 gloads).
    auto stageA = [&](int e, int kt, int nb) {
        const int r = w * 16 + e * 8;
        gload16(&Xb[(size_t)(m0 + r + l3) * HH + kt * 64 + cl], &As[nb][r * 64]);
    };
    auto stageB = [&](int e, int kt, int nb) {
        const int r = w * 32 + e * 8;
        gload16(&Wtz[(size_t)(n0 + r + l3) * HH + kt * 64 + cl], &Bs[nb][r * 64]);
    };

    f32x4 acc[4][4];
    #pragma unroll
    for (int i = 0; i < 4; i++)
        #pragma unroll
        for (int j = 0; j < 4; j++) acc[i][j] = f32x4{0.f, 0.f, 0.f, 0.f};

    // prologue: stage K-tile 0 into buffer 0 (6 gloads per wave).
    stageA(0, 0, 0); stageA(1, 0, 0);
    stageB(0, 0, 0); stageB(1, 0, 0); stageB(2, 0, 0); stageB(3, 0, 0);

    bf16x8 af[4], bf[2];

    for (int kt = 0; kt < 16; kt++) {
        const int cur = kt & 1, nb = cur ^ 1;
        const bool pf = (kt < 15);

        // ---------- phase 1: (kc=0, n-half 0) ----------
        if (pf) { stageA(0, kt + 1, nb); stageA(1, kt + 1, nb); WAITV2(); }
        else    { WAITV0(); }
        SBAR();                      // tile kt fully staged (all waves)
        #pragma unroll
        for (int mi = 0; mi < 4; mi++)
            af[mi] = *(const bf16x8*)&As[cur][(wm * 64 + mi * 16 + lr) * 64
                                              + (quad ^ c7) * 8];
        #pragma unroll
        for (int j = 0; j < 2; j++)
            bf[j] = *(const bf16x8*)&Bs[cur][(wn * 64 + j * 16 + lr) * 64
                                             + (quad ^ c7) * 8];
        LGKM0(); SCHEDB();
        __builtin_amdgcn_s_setprio(1);
        if (z != 2) {
            #pragma unroll
            for (int mi = 0; mi < 4; mi++)
                #pragma unroll
                for (int j = 0; j < 2; j++)
                    acc[mi][j] = __builtin_amdgcn_mfma_f32_16x16x32_bf16(
                        bf[j], af[mi], acc[mi][j], 0, 0, 0);
        } else {
            #pragma unroll
            for (int mi = 0; mi < 4; mi++)
                #pragma unroll
                for (int j = 0; j < 2; j++)
                    acc[mi][j] = __builtin_amdgcn_mfma_f32_16x16x32_bf16(
                        af[mi], bf[j], acc[mi][j], 0, 0, 0);
        }
        __builtin_amdgcn_s_setprio(0);
        SBAR();

        // ---------- phase 2: (kc=0, n-half 1) ----------
        if (pf) { stageB(0, kt + 1, nb); stageB(1, kt + 1, nb); }
        #pragma unroll
        for (int j = 0; j < 2; j++)
            bf[j] = *(const bf16x8*)&Bs[cur][(wn * 64 + (2 + j) * 16 + lr) * 64
                                             + (quad ^ c7) * 8];
        LGKM0(); SCHEDB();
        __builtin_amdgcn_s_setprio(1);
        if (z != 2) {
            #pragma unroll
            for (int mi = 0; mi < 4; mi++)
                #pragma unroll
                for (int j = 0; j < 2; j++)
                    acc[mi][2 + j] = __builtin_amdgcn_mfma_f32_16x16x32_bf16(
                        bf[j], af[mi], acc[mi][2 + j], 0, 0, 0);
        } else {
            #pragma unroll
            for (int mi = 0; mi < 4; mi++)
                #pragma unroll
                for (int j = 0; j < 2; j++)
                    acc[mi][2 + j] = __builtin_amdgcn_mfma_f32_16x16x32_bf16(
                        af[mi], bf[j], acc[mi][2 + j], 0, 0, 0);
        }
        __builtin_amdgcn_s_setprio(0);
        SBAR();

        // ---------- phase 3: (kc=1, n-half 0) ----------
        if (pf) stageB(2, kt + 1, nb);
        #pragma unroll
        for (int mi = 0; mi < 4; mi++)
            af[mi] = *(const bf16x8*)&As[cur][(wm * 64 + mi * 16 + lr) * 64
                                              + ((4 + quad) ^ c7) * 8];
        #pragma unroll
        for (int j = 0; j < 2; j++)
            bf[j] = *(const bf16x8*)&Bs[cur][(wn * 64 + j * 16 + lr) * 64
                                             + ((4 + quad) ^ c7) * 8];
        LGKM0(); SCHEDB();
        __builtin_amdgcn_s_setprio(1);
        if (z != 2) {
            #pragma unroll
            for (int mi = 0; mi < 4; mi++)
                #pragma unroll
                for (int j = 0; j < 2; j++)
                    acc[mi][j] = __builtin_amdgcn_mfma_f32_16x16x32_bf16(
                        bf[j], af[mi], acc[mi][j], 0, 0, 0);
        } else {
            #pragma unroll
            for (int mi = 0; mi < 4; mi++)
                #pragma unroll
                for (int j = 0; j < 2; j++)
                    acc[mi][j] = __builtin_amdgcn_mfma_f32_16x16x32_bf16(
                        af[mi], bf[j], acc[mi][j], 0, 0, 0);
        }
        __builtin_amdgcn_s_setprio(0);
        SBAR();

        // ---------- phase 4: (kc=1, n-half 1) ----------
        if (pf) stageB(3, kt + 1, nb);
        #pragma unroll
        for (int j = 0; j < 2; j++)
            bf[j] = *(const bf16x8*)&Bs[cur][(wn * 64 + (2 + j) * 16 + lr) * 64
                                             + ((4 + quad) ^ c7) * 8];
        LGKM0(); SCHEDB();
        __builtin_amdgcn_s_setprio(1);
        if (z != 2) {
            #pragma unroll
            for (int mi = 0; mi < 4; mi++)
                #pragma unroll
                for (int j = 0; j < 2; j++)
                    acc[mi][2 + j] = __builtin_amdgcn_mfma_f32_16x16x32_bf16(
                        bf[j], af[mi], acc[mi][2 + j], 0, 0, 0);
        } else {
            #pragma unroll
            for (int mi = 0; mi < 4; mi++)
                #pragma unroll
                for (int j = 0; j < 2; j++)
                    acc[mi][2 + j] = __builtin_amdgcn_mfma_f32_16x16x32_bf16(
                        af[mi], bf[j], acc[mi][2 + j], 0, 0, 0);
        }
        __builtin_amdgcn_s_setprio(0);
        SBAR();
    }

    // ---- epilogue: LDS bounce -> full-line stores.
    // Wave-private 8KB region: Bs flat = 64KB = 8 waves x 8KB. All compute
    // reads of Bs finished before the last phase-4 trailing SBAR.
    // XOR swizzle byte ^= (row&7)<<4 (16B-granular, bank-spread).
    u16* eb = (u16*)&Bs[0][0] + w * 4096;

    if (z != 2) {
        // acc = D^T: lr = local s, (ni,quad,reg) = d. Dump as [s][d] 64x64.
        const float cs = (z == 0) ? 0.18033688011112042f : 1.0f;
        #pragma unroll
        for (int mi = 0; mi < 4; mi++) {
            const int rr = mi * 16 + lr;
            #pragma unroll
            for (int ni = 0; ni < 4; ni++) {
                const int nb2 = n0 + wn * 64 + ni * 16 + quad * 4;
                float4 bb4 = *(const float4*)&bias[nb2];
                ushort4 vs;
                vs.x = f2b((acc[mi][ni][0] + bb4.x) * cs);
                vs.y = f2b((acc[mi][ni][1] + bb4.y) * cs);
                vs.z = f2b((acc[mi][ni][2] + bb4.z) * cs);
                vs.w = f2b((acc[mi][ni][3] + bb4.w) * cs);
                const int cbyte = (ni * 16 + quad * 4) * 2;
                *(ushort4*)((char*)eb + rr * 128 + (cbyte ^ ((rr & 7) << 4))) = vs;
            }
        }
    } else {
        // acc = D: lr = local d, (mi,quad,reg) = s. Dump as [d][s] 64x64.
        #pragma unroll
        for (int mi = 0; mi < 4; mi++) {
            #pragma unroll
            for (int ni = 0; ni < 4; ni++) {
                const int n = n0 + wn * 64 + ni * 16 + lr;
                const float bv4 = bias[n];
                ushort4 vs;
                vs.x = f2b(acc[mi][ni][0] + bv4);
                vs.y = f2b(acc[mi][ni][1] + bv4);
                vs.z = f2b(acc[mi][ni][2] + bv4);
                vs.w = f2b(acc[mi][ni][3] + bv4);
                const int rr = ni * 16 + lr;
                const int cbyte = (mi * 16 + quad * 4) * 2;
                *(ushort4*)((char*)eb + rr * 128 + (cbyte ^ ((rr & 7) << 4))) = vs;
            }
        }
    }
    LGKM0();
    SCHEDB();

    // read back rows; 8 lanes x 16B = one full 128B output line per row.
    {
        const int rg = lane >> 3;                 // row-in-group 0..7
        const int cb = (lane & 7) * 16;           // byte col 0..112
        const int h = (n0 + wn * 64) >> 6;        // head = by*4 + wn
        if (z != 2) {
            u16* dst = (z == 0) ? Qw : Kw;
            #pragma unroll
            for (int p = 0; p < 8; p++) {
                const int r2 = p * 8 + rg;        // local s
                bf16x8 rowv = *(const bf16x8*)
                    ((char*)eb + r2 * 128 + (cb ^ ((r2 & 7) << 4)));
                const int sg = m0 + wm * 64 + r2;
                const int b = sg >> 11, s = sg & 2047;
                *(bf16x8*)&dst[((size_t)(b * NHH + h) * SS + s) * HDD + (cb >> 1)]
                    = rowv;
            }
        } else {
            const int mb = m0 + wm * 64;
            const int b = mb >> 11, s0 = mb & 2047;
            #pragma unroll
            for (int p = 0; p < 8; p++) {
                const int r2 = p * 8 + rg;        // local d
                bf16x8 rowv = *(const bf16x8*)
                    ((char*)eb + r2 * 128 + (cb ^ ((r2 & 7) << 4)));
                *(bf16x8*)&Vw[((size_t)(b * NHH + h) * HDD + r2) * SS + s0 + (cb >> 1)]
                    = rowv;
            }
        }
    }
}

// ---------------------------------------------------------------------------
// attn (r7, measured 82.7us): flash attention, M=0 softmax (p = exp2(s),
// Q pre-scaled). 512 threads = 8 waves, 32 q-rows/wave -> 256 q/block,
// grid 512. 32x32x16 MFMA, swapped QK^T; P stays in registers:
// 16 v_cvt_pk_bf16_f32 + 8 v_permlane32_swap -> 4 PV A-frags per k-tile.
// Double-buffered async K/V staging (XOR-swizzled), no P LDS slab.
// ---------------------------------------------------------------------------
__global__ __launch_bounds__(512, 4) void attn(
    const u16* __restrict__ Qb, const u16* __restrict__ Kb,
    const u16* __restrict__ Vtb, float* __restrict__ Out)
{
    // hh = bid&63: all 8 q-blocks of a head land on XCD (hh&7).
    const int bid = blockIdx.x;
    const int hh = bid & 63, qt = bid >> 6;      // qt 0..7
    const int b = hh >> 4, h = hh & 15;
    const size_t hb = (size_t)hh * SS * HDD;

    __shared__ __align__(16) u16 Ks[2][64 * 64];
    __shared__ __align__(16) u16 Vs[2][64 * 64];

    const int t = threadIdx.x;
    const int w = t >> 6, lane = t & 63;
    const int q32 = lane & 31, hi = lane >> 5;
    const int l3 = lane >> 3, c7 = lane & 7;
    const int cl = (c7 ^ l3) * 8;          // swizzled source column (u16)

    // Q B-frags (col = q = lane&31, k = d = ds*16 + hi*8 + j), kept in VGPRs.
    bf16x8 qf[4];
    {
        const size_t qrow = (size_t)(qt * 256 + w * 32 + q32);
        #pragma unroll
        for (int ds = 0; ds < 4; ds++)
            qf[ds] = *(const bf16x8*)&Qb[hb + qrow * HDD + ds * 16 + hi * 8];
    }

    // preload tile 0 into buffer 0: wave w stages rows w*8..w*8+7 of K and V^T
    {
        const int r8 = w * 8 + l3;
        gload16(&Kb [hb + (size_t)r8 * HDD + cl], &Ks[0][w * 8 * 64]);
        gload16(&Vtb[hb + (size_t)r8 * SS + cl],  &Vs[0][w * 8 * 64]);
    }
    __syncthreads();

    float lsum = 0.f;          // partial row-sum for q = q32 (this half)
    f32x16 oc0 = {}, oc1 = {};

    for (int kt = 0; kt < SS / 64; kt++) {
        const int bb = kt & 1;
        if (kt + 1 < SS / 64) {   // prefetch next tile into the other buffer
            const int r8 = w * 8 + l3;
            gload16(&Kb [hb + (size_t)((kt + 1) * 64 + r8) * HDD + cl],
                    &Ks[bb ^ 1][w * 8 * 64]);
            gload16(&Vtb[hb + (size_t)r8 * SS + (kt + 1) * 64 + cl],
                    &Vs[bb ^ 1][w * 8 * 64]);
        }

        // ---- S^T = K Q^T: two 32x32 tiles (k-rows 0..31, 32..63), q=lane&31
        f32x16 sc0 = {}, sc1 = {};
        __builtin_amdgcn_s_setprio(1);
        #pragma unroll
        for (int ds = 0; ds < 4; ds++) {
            const int ph = ((ds * 2 + hi) ^ c7) * 8;
            bf16x8 kf0 = *(const bf16x8*)&Ks[bb][q32 * 64 + ph];
            bf16x8 kf1 = *(const bf16x8*)&Ks[bb][(32 + q32) * 64 + ph];
            sc0 = __builtin_amdgcn_mfma_f32_32x32x16_bf16(kf0, qf[ds], sc0, 0, 0, 0);
            sc1 = __builtin_amdgcn_mfma_f32_32x32x16_bf16(kf1, qf[ds], sc1, 0, 0, 0);
        }
        __builtin_amdgcn_s_setprio(0);

        // ---- p = exp2(s); in-register pack to PV A-frags via cvt_pk+permlane.
        // lane owns P[k = kb*32 + (r&3)+8*(r>>2)+4*hi][q = q32].
        union PU { u32x4 u; bf16x8 v; } pa[4];
        #pragma unroll
        for (int kb = 0; kb < 2; kb++) {
            const f32x16 s = kb ? sc1 : sc0;
            float p[16];
            #pragma unroll
            for (int r = 0; r < 16; r++) p[r] = __builtin_amdgcn_exp2f(s[r]);
            lsum += ((((p[0] + p[1]) + (p[2] + p[3]))
                    + ((p[4] + p[5]) + (p[6] + p[7])))
                   + (((p[8] + p[9]) + (p[10] + p[11]))
                    + ((p[12] + p[13]) + (p[14] + p[15]))));
            u32 x0, x1, x2, x3, y0, y1, y2, y3;
            asm("v_cvt_pk_bf16_f32 %0, %1, %2" : "=v"(x0) : "v"(p[0]),  "v"(p[1]));
            asm("v_cvt_pk_bf16_f32 %0, %1, %2" : "=v"(x1) : "v"(p[2]),  "v"(p[3]));
            asm("v_cvt_pk_bf16_f32 %0, %1, %2" : "=v"(y0) : "v"(p[4]),  "v"(p[5]));
            asm("v_cvt_pk_bf16_f32 %0, %1, %2" : "=v"(y1) : "v"(p[6]),  "v"(p[7]));
            asm("v_cvt_pk_bf16_f32 %0, %1, %2" : "=v"(x2) : "v"(p[8]),  "v"(p[9]));
            asm("v_cvt_pk_bf16_f32 %0, %1, %2" : "=v"(x3) : "v"(p[10]), "v"(p[11]));
            asm("v_cvt_pk_bf16_f32 %0, %1, %2" : "=v"(y2) : "v"(p[12]), "v"(p[13]));
            asm("v_cvt_pk_bf16_f32 %0, %1, %2" : "=v"(y3) : "v"(p[14]), "v"(p[15]));
            // swap hi-half(x) <-> lo-half(y): x' = frag reg{0,1}, y' = reg{2,3}
            asm("v_permlane32_swap_b32 %0, %1" : "+v"(x0), "+v"(y0));
            asm("v_permlane32_swap_b32 %0, %1" : "+v"(x1), "+v"(y1));
            asm("v_permlane32_swap_b32 %0, %1" : "+v"(x2), "+v"(y2));
            asm("v_permlane32_swap_b32 %0, %1" : "+v"(x3), "+v"(y3));
            pa[kb * 2 + 0].u = u32x4{x0, x1, y0, y1};   // k-step 2kb   (k 0..15)
            pa[kb * 2 + 1].u = u32x4{x2, x3, y2, y3};   // k-step 2kb+1 (k 16..31)
        }

        // ---- O += P V (A = P rows q, B = V^T rows d, k-steps of 16)
        __builtin_amdgcn_s_setprio(1);
        #pragma unroll
        for (int ks = 0; ks < 4; ks++) {
            const int ph = ((ks * 2 + hi) ^ c7) * 8;
            bf16x8 vf0 = *(const bf16x8*)&Vs[bb][q32 * 64 + ph];
            bf16x8 vf1 = *(const bf16x8*)&Vs[bb][(32 + q32) * 64 + ph];
            oc0 = __builtin_amdgcn_mfma_f32_32x32x16_bf16(pa[ks].v, vf0, oc0, 0, 0, 0);
            oc1 = __builtin_amdgcn_mfma_f32_32x32x16_bf16(pa[ks].v, vf1, oc1, 0, 0, 0);
        }
        __builtin_amdgcn_s_setprio(0);
        __syncthreads();   // reads of buf bb done; prefetch into bb^1 landed
    }

    // ---- finalize l: q's row-sum is split across lanes q32 and q32+32.
    lsum += __shfl_xor(lsum, 32);
    const float linv = 1.0f / lsum;

    // oc rows are q = (r&3)+8*(r>>2)+4*hi; inv lives at lane q (lo half ok).
    #pragma unroll
    for (int r = 0; r < 16; r++) {
        const int cr = (r & 3) + 8 * (r >> 2) + 4 * hi;
        const float inv = __shfl(linv, cr);
        const int rq = qt * 256 + w * 32 + cr;
        float* o = &Out[((size_t)(b * SS + rq)) * HH + h * HDD + q32];
        o[0]  = oc0[r] * inv;
        o[32] = oc1[r] * inv;
    }
}

// ---------------------------------------------------------------------------
extern "C" void kernel_launch(void* const* d_in, const int* in_sizes, int n_in,
                              void* d_out, int out_size, void* d_ws, size_t ws_size,
                              hipStream_t stream) {
    const float* X  = (const float*)d_in[0];
    const float* Wq = (const float*)d_in[1];
    const float* bq = (const float*)d_in[2];
    const float* Wk = (const float*)d_in[3];
    const float* bk = (const float*)d_in[4];
    const float* Wv = (const float*)d_in[5];
    const float* bv = (const float*)d_in[6];
    float* Out = (float*)d_out;

    const size_t elems = (size_t)BB * SS * HH;  // 8,388,608
    u16* Qw = (u16*)d_ws;                        // Q (pre-scaled) [b,h,s,d]
    u16* Kw = Qw + elems;                        // K [b,h,s,d]
    u16* Vw = Kw + elems;                        // V^T [b,h,d,s]
    // Xb/Wt scratch in d_out (23.1 MB < 33.5 MB; attn fully overwrites).
    u16* Xb = (u16*)d_out;
    u16* Wt = Xb + elems;

    conv<<<dim3(4096 + 3072), 256, 0, stream>>>(X, Wq, Wk, Wv, Xb, Wt);
    qkv_gemm<<<dim3(64, 4, 3), 512, 0, stream>>>(Xb, Wt, bq, bk, bv, Qw, Kw, Vw);
    attn<<<dim3(512), 512, 0, stream>>>(Qw, Kw, Vw, Out);
}

// Round 8
// 239.633 us; speedup vs baseline: 1.1757x; 1.1757x over previous
//
#include <hip/hip_runtime.h>
#include <hip/hip_bf16.h>

// BertSelfAttention (no mask). B=4, S=2048, H=1024, NH=16, HD=64. fp32 I/O.
// Round 14: best-known-components build. qkv_gemm reverted to r11 exact
// (128x128 2-phase dbuf, counted vmcnt(8), LDS-bounce full-line epilogue;
// r13's 4-phase was barrier-stall-bound at 115us). attn = r7 (measured
// 82.7us: 512 thr, 32 q/wave, dbuf + __syncthreads). conv unchanged.
#define BB  4
#define SS  2048
#define HH  1024
#define NHH 16
#define HDD 64

typedef unsigned short u16;
typedef unsigned int   u32;
using bf16x8 = __attribute__((ext_vector_type(8))) short;   // 8 bf16 = 4 VGPRs
using f32x4  = __attribute__((ext_vector_type(4))) float;   // MFMA C/D 16x16
using f32x16 = __attribute__((ext_vector_type(16))) float;  // MFMA C/D 32x32
using u32x4  = __attribute__((ext_vector_type(4))) u32;

#define SBAR()   asm volatile("s_barrier" ::: "memory")
#define WAITV0() asm volatile("s_waitcnt vmcnt(0)" ::: "memory")
#define WAITV8() asm volatile("s_waitcnt vmcnt(8)" ::: "memory")
#define LGKM0()  asm volatile("s_waitcnt lgkmcnt(0)" ::: "memory")
#define SCHEDB() __builtin_amdgcn_sched_barrier(0)

// fp32 -> bf16 RNE.
__device__ __forceinline__ u16 f2b(float f) {
    union { float f; u32 u; } x; x.f = f;
    return (u16)((x.u + 0x7fffu + ((x.u >> 16) & 1u)) >> 16);
}

// async 16B global -> LDS (dest = wave-uniform base + lane*16).
__device__ __forceinline__ void gload16(const u16* g, u16* l) {
    __builtin_amdgcn_global_load_lds(
        (const __attribute__((address_space(1))) void*)g,
        (__attribute__((address_space(3))) void*)l, 16, 0, 0);
}

// ---------------------------------------------------------------------------
// conv: fused input conversion.
//   blocks [0,4096):      X fp32 -> bf16 straight copy (8 elems/thread)
//   blocks [4096,7168):   W[k][n] fp32 -> Wt[n][k] bf16 (32x32 transpose)
// ---------------------------------------------------------------------------
__global__ __launch_bounds__(256) void conv(
    const float* __restrict__ X,
    const float* __restrict__ Wq, const float* __restrict__ Wk,
    const float* __restrict__ Wv,
    u16* __restrict__ Xb, u16* __restrict__ Wt)
{
    const int bid = blockIdx.x;
    const int t = threadIdx.x;
    if (bid < 4096) {
        const int i = bid * 256 + t;
        float4 a = ((const float4*)X)[i * 2];
        float4 b = ((const float4*)X)[i * 2 + 1];
        ushort4 s0, s1;
        s0.x = f2b(a.x); s0.y = f2b(a.y); s0.z = f2b(a.z); s0.w = f2b(a.w);
        s1.x = f2b(b.x); s1.y = f2b(b.y); s1.z = f2b(b.z); s1.w = f2b(b.w);
        ((ushort4*)Xb)[i * 2] = s0;
        ((ushort4*)Xb)[i * 2 + 1] = s1;
        return;
    }
    const int idx = bid - 4096;
    const int z = idx >> 10, rem = idx & 1023;
    const int k0 = (rem >> 5) * 32, n0 = (rem & 31) * 32;
    const float* W = (z == 0) ? Wq : (z == 1) ? Wk : Wv;
    u16* out = Wt + (size_t)z * HH * HH;
    __shared__ float T[32][33];
    {
        const int kl = t >> 3, n4 = (t & 7) * 4;
        float4 v = *(const float4*)&W[(size_t)(k0 + kl) * HH + n0 + n4];
        T[n4 + 0][kl] = v.x; T[n4 + 1][kl] = v.y;
        T[n4 + 2][kl] = v.z; T[n4 + 3][kl] = v.w;
    }
    __syncthreads();
    {
        const int nl = t >> 3, k4 = (t & 7) * 4;
        ushort4 s;
        s.x = f2b(T[nl][k4 + 0]); s.y = f2b(T[nl][k4 + 1]);
        s.z = f2b(T[nl][k4 + 2]); s.w = f2b(T[nl][k4 + 3]);
        *(ushort4*)&out[(size_t)(n0 + nl) * HH + k0 + k4] = s;
    }
}

// ---------------------------------------------------------------------------
// qkv_gemm (r11 exact): 128x128 tile, BK=64, global_load_lds + XOR swizzle,
// 4 waves 2x2. Double-buffered LDS + counted vmcnt(8) + raw barriers.
// Epilogue: per-wave 64x64 acc tile -> wave-private LDS bounce ->
// full-128B-line global stores (kills HBM write RMW amplification).
// z<2 (Q,K): operands SWAPPED -> acc = D^T (regs step d) -> [b,h,s,d] rows.
//            Q pre-scaled by 0.125*log2(e).
// z=2 (V):   normal order (regs step s) -> V^T [b,h,d,s] rows.
// ---------------------------------------------------------------------------
__global__ __launch_bounds__(256, 2) void qkv_gemm(
    const u16* __restrict__ Xb, const u16* __restrict__ Wtb,
    const float* __restrict__ bq, const float* __restrict__ bk,
    const float* __restrict__ bv,
    u16* __restrict__ Qw, u16* __restrict__ Kw, u16* __restrict__ Vw)
{
    const int z  = blockIdx.z;
    const float* bias = (z == 0) ? bq : (z == 1) ? bk : bv;
    const int m0 = blockIdx.x * 128, n0 = blockIdx.y * 128;

    __shared__ __align__(16) u16 Xs[2][128 * 64];
    __shared__ __align__(16) u16 Ws[2][128 * 64];

    const int t = threadIdx.x;
    const int w = t >> 6, lane = t & 63, lr = lane & 15, quad = lane >> 4;
    const int l3 = lane >> 3, c7 = lane & 7;
    const int cl = (c7 ^ l3) * 8;          // swizzled source column (u16)
    const int wm = w >> 1, wn = w & 1;

    const u16* Wtz = Wtb + (size_t)z * HH * HH;

    f32x4 acc[4][4];
    #pragma unroll
    for (int i = 0; i < 4; i++)
        #pragma unroll
        for (int j = 0; j < 4; j++) acc[i][j] = f32x4{0.f, 0.f, 0.f, 0.f};

    // prologue: stage tile 0 into buffer 0 (8 gloads per wave).
    #pragma unroll
    for (int e = 0; e < 4; e++) {
        const int r = w * 32 + e * 8 + l3;
        gload16(&Xb [(size_t)(m0 + r) * HH + cl], &Xs[0][(w * 32 + e * 8) * 64]);
        gload16(&Wtz[(size_t)(n0 + r) * HH + cl], &Ws[0][(w * 32 + e * 8) * 64]);
    }

    for (int kt = 0; kt < 16; kt++) {
        const int cur = kt & 1;
        if (kt < 15) {
            const int k0 = (kt + 1) * 64;
            #pragma unroll
            for (int e = 0; e < 4; e++) {
                const int r = w * 32 + e * 8 + l3;
                gload16(&Xb [(size_t)(m0 + r) * HH + k0 + cl],
                        &Xs[cur ^ 1][(w * 32 + e * 8) * 64]);
                gload16(&Wtz[(size_t)(n0 + r) * HH + k0 + cl],
                        &Ws[cur ^ 1][(w * 32 + e * 8) * 64]);
            }
            WAITV8();     // tile kt's 8 loads done; kt+1's 8 stay in flight
        } else {
            WAITV0();
        }
        SBAR();
        SCHEDB();

        #pragma unroll
        for (int kc = 0; kc < 2; kc++) {
            bf16x8 af[4], bfr[4];
            const int ph = ((kc * 4 + quad) ^ c7) * 8;
            #pragma unroll
            for (int mi = 0; mi < 4; mi++)
                af[mi] = *(const bf16x8*)&Xs[cur][(wm * 64 + mi * 16 + lr) * 64 + ph];
            #pragma unroll
            for (int ni = 0; ni < 4; ni++)
                bfr[ni] = *(const bf16x8*)&Ws[cur][(wn * 64 + ni * 16 + lr) * 64 + ph];
            if (z != 2) {   // swapped: acc[mi][ni] = (W.X^T) tile = D^T
                #pragma unroll
                for (int mi = 0; mi < 4; mi++)
                    #pragma unroll
                    for (int ni = 0; ni < 4; ni++)
                        acc[mi][ni] = __builtin_amdgcn_mfma_f32_16x16x32_bf16(
                            bfr[ni], af[mi], acc[mi][ni], 0, 0, 0);
            } else {
                #pragma unroll
                for (int mi = 0; mi < 4; mi++)
                    #pragma unroll
                    for (int ni = 0; ni < 4; ni++)
                        acc[mi][ni] = __builtin_amdgcn_mfma_f32_16x16x32_bf16(
                            af[mi], bfr[ni], acc[mi][ni], 0, 0, 0);
            }
        }
        SCHEDB();
        SBAR();           // all waves done reading buf cur (reused at kt+2)
    }

    // ---- epilogue: LDS bounce -> full-line stores.
    // Wave-private 8KB region in buffer-0 LDS. XOR swizzle byte ^= (row&7)<<4.
    u16* eb = (w < 2 ? &Xs[0][0] : &Ws[0][0]) + (w & 1) * 4096;

    if (z != 2) {
        // acc = D^T: lr = local s, (ni,quad,reg) = d. Dump as [s][d] 64x64.
        const float cs = (z == 0) ? 0.18033688011112042f : 1.0f;
        #pragma unroll
        for (int mi = 0; mi < 4; mi++) {
            const int rr = mi * 16 + lr;
            #pragma unroll
            for (int ni = 0; ni < 4; ni++) {
                const int nb = n0 + wn * 64 + ni * 16 + quad * 4;
                float4 bb4 = *(const float4*)&bias[nb];
                ushort4 vs;
                vs.x = f2b((acc[mi][ni][0] + bb4.x) * cs);
                vs.y = f2b((acc[mi][ni][1] + bb4.y) * cs);
                vs.z = f2b((acc[mi][ni][2] + bb4.z) * cs);
                vs.w = f2b((acc[mi][ni][3] + bb4.w) * cs);
                const int cbyte = (ni * 16 + quad * 4) * 2;
                *(ushort4*)((char*)eb + rr * 128 + (cbyte ^ ((rr & 7) << 4))) = vs;
            }
        }
    } else {
        // acc = D: lr = local d, (mi,quad,reg) = s. Dump as [d][s] 64x64.
        #pragma unroll
        for (int mi = 0; mi < 4; mi++) {
            #pragma unroll
            for (int ni = 0; ni < 4; ni++) {
                const int n = n0 + wn * 64 + ni * 16 + lr;
                const float bv4 = bias[n];
                ushort4 vs;
                vs.x = f2b(acc[mi][ni][0] + bv4);
                vs.y = f2b(acc[mi][ni][1] + bv4);
                vs.z = f2b(acc[mi][ni][2] + bv4);
                vs.w = f2b(acc[mi][ni][3] + bv4);
                const int rr = ni * 16 + lr;
                const int cbyte = (mi * 16 + quad * 4) * 2;
                *(ushort4*)((char*)eb + rr * 128 + (cbyte ^ ((rr & 7) << 4))) = vs;
            }
        }
    }
    LGKM0();
    SCHEDB();

    // read back rows; 8 lanes x 16B = one full 128B output line per row.
    {
        const int rg = lane >> 3;                 // row-in-group 0..7
        const int cb = (lane & 7) * 16;           // byte col 0..112
        const int h = (n0 + wn * 64) >> 6;        // head (64-aligned n-chunk)
        if (z != 2) {
            u16* dst = (z == 0) ? Qw : Kw;
            #pragma unroll
            for (int p = 0; p < 8; p++) {
                const int r2 = p * 8 + rg;        // local s
                bf16x8 rowv = *(const bf16x8*)
                    ((char*)eb + r2 * 128 + (cb ^ ((r2 & 7) << 4)));
                const int sg = m0 + wm * 64 + r2;
                const int b = sg >> 11, s = sg & 2047;
                *(bf16x8*)&dst[((size_t)(b * NHH + h) * SS + s) * HDD + (cb >> 1)]
                    = rowv;
            }
        } else {
            const int mb = m0 + wm * 64;
            const int b = mb >> 11, s0 = mb & 2047;
            #pragma unroll
            for (int p = 0; p < 8; p++) {
                const int r2 = p * 8 + rg;        // local d
                bf16x8 rowv = *(const bf16x8*)
                    ((char*)eb + r2 * 128 + (cb ^ ((r2 & 7) << 4)));
                *(bf16x8*)&Vw[((size_t)(b * NHH + h) * HDD + r2) * SS + s0 + (cb >> 1)]
                    = rowv;
            }
        }
    }
}

// ---------------------------------------------------------------------------
// attn (r7, measured 82.7us): flash attention, M=0 softmax (p = exp2(s),
// Q pre-scaled). 512 threads = 8 waves, 32 q-rows/wave -> 256 q/block,
// grid 512. 32x32x16 MFMA, swapped QK^T; P stays in registers:
// 16 v_cvt_pk_bf16_f32 + 8 v_permlane32_swap -> 4 PV A-frags per k-tile.
// Double-buffered async K/V staging (XOR-swizzled), no P LDS slab.
// ---------------------------------------------------------------------------
__global__ __launch_bounds__(512, 4) void attn(
    const u16* __restrict__ Qb, const u16* __restrict__ Kb,
    const u16* __restrict__ Vtb, float* __restrict__ Out)
{
    // hh = bid&63: all 8 q-blocks of a head land on XCD (hh&7).
    const int bid = blockIdx.x;
    const int hh = bid & 63, qt = bid >> 6;      // qt 0..7
    const int b = hh >> 4, h = hh & 15;
    const size_t hb = (size_t)hh * SS * HDD;

    __shared__ __align__(16) u16 Ks[2][64 * 64];
    __shared__ __align__(16) u16 Vs[2][64 * 64];

    const int t = threadIdx.x;
    const int w = t >> 6, lane = t & 63;
    const int q32 = lane & 31, hi = lane >> 5;
    const int l3 = lane >> 3, c7 = lane & 7;
    const int cl = (c7 ^ l3) * 8;          // swizzled source column (u16)

    // Q B-frags (col = q = lane&31, k = d = ds*16 + hi*8 + j), kept in VGPRs.
    bf16x8 qf[4];
    {
        const size_t qrow = (size_t)(qt * 256 + w * 32 + q32);
        #pragma unroll
        for (int ds = 0; ds < 4; ds++)
            qf[ds] = *(const bf16x8*)&Qb[hb + qrow * HDD + ds * 16 + hi * 8];
    }

    // preload tile 0 into buffer 0: wave w stages rows w*8..w*8+7 of K and V^T
    {
        const int r8 = w * 8 + l3;
        gload16(&Kb [hb + (size_t)r8 * HDD + cl], &Ks[0][w * 8 * 64]);
        gload16(&Vtb[hb + (size_t)r8 * SS + cl],  &Vs[0][w * 8 * 64]);
    }
    __syncthreads();

    float lsum = 0.f;          // partial row-sum for q = q32 (this half)
    f32x16 oc0 = {}, oc1 = {};

    for (int kt = 0; kt < SS / 64; kt++) {
        const int bb = kt & 1;
        if (kt + 1 < SS / 64) {   // prefetch next tile into the other buffer
            const int r8 = w * 8 + l3;
            gload16(&Kb [hb + (size_t)((kt + 1) * 64 + r8) * HDD + cl],
                    &Ks[bb ^ 1][w * 8 * 64]);
            gload16(&Vtb[hb + (size_t)r8 * SS + (kt + 1) * 64 + cl],
                    &Vs[bb ^ 1][w * 8 * 64]);
        }

        // ---- S^T = K Q^T: two 32x32 tiles (k-rows 0..31, 32..63), q=lane&31
        f32x16 sc0 = {}, sc1 = {};
        __builtin_amdgcn_s_setprio(1);
        #pragma unroll
        for (int ds = 0; ds < 4; ds++) {
            const int ph = ((ds * 2 + hi) ^ c7) * 8;
            bf16x8 kf0 = *(const bf16x8*)&Ks[bb][q32 * 64 + ph];
            bf16x8 kf1 = *(const bf16x8*)&Ks[bb][(32 + q32) * 64 + ph];
            sc0 = __builtin_amdgcn_mfma_f32_32x32x16_bf16(kf0, qf[ds], sc0, 0, 0, 0);
            sc1 = __builtin_amdgcn_mfma_f32_32x32x16_bf16(kf1, qf[ds], sc1, 0, 0, 0);
        }
        __builtin_amdgcn_s_setprio(0);

        // ---- p = exp2(s); in-register pack to PV A-frags via cvt_pk+permlane.
        // lane owns P[k = kb*32 + (r&3)+8*(r>>2)+4*hi][q = q32].
        union PU { u32x4 u; bf16x8 v; } pa[4];
        #pragma unroll
        for (int kb = 0; kb < 2; kb++) {
            const f32x16 s = kb ? sc1 : sc0;
            float p[16];
            #pragma unroll
            for (int r = 0; r < 16; r++) p[r] = __builtin_amdgcn_exp2f(s[r]);
            lsum += ((((p[0] + p[1]) + (p[2] + p[3]))
                    + ((p[4] + p[5]) + (p[6] + p[7])))
                   + (((p[8] + p[9]) + (p[10] + p[11]))
                    + ((p[12] + p[13]) + (p[14] + p[15]))));
            u32 x0, x1, x2, x3, y0, y1, y2, y3;
            asm("v_cvt_pk_bf16_f32 %0, %1, %2" : "=v"(x0) : "v"(p[0]),  "v"(p[1]));
            asm("v_cvt_pk_bf16_f32 %0, %1, %2" : "=v"(x1) : "v"(p[2]),  "v"(p[3]));
            asm("v_cvt_pk_bf16_f32 %0, %1, %2" : "=v"(y0) : "v"(p[4]),  "v"(p[5]));
            asm("v_cvt_pk_bf16_f32 %0, %1, %2" : "=v"(y1) : "v"(p[6]),  "v"(p[7]));
            asm("v_cvt_pk_bf16_f32 %0, %1, %2" : "=v"(x2) : "v"(p[8]),  "v"(p[9]));
            asm("v_cvt_pk_bf16_f32 %0, %1, %2" : "=v"(x3) : "v"(p[10]), "v"(p[11]));
            asm("v_cvt_pk_bf16_f32 %0, %1, %2" : "=v"(y2) : "v"(p[12]), "v"(p[13]));
            asm("v_cvt_pk_bf16_f32 %0, %1, %2" : "=v"(y3) : "v"(p[14]), "v"(p[15]));
            // swap hi-half(x) <-> lo-half(y): x' = frag reg{0,1}, y' = reg{2,3}
            asm("v_permlane32_swap_b32 %0, %1" : "+v"(x0), "+v"(y0));
            asm("v_permlane32_swap_b32 %0, %1" : "+v"(x1), "+v"(y1));
            asm("v_permlane32_swap_b32 %0, %1" : "+v"(x2), "+v"(y2));
            asm("v_permlane32_swap_b32 %0, %1" : "+v"(x3), "+v"(y3));
            pa[kb * 2 + 0].u = u32x4{x0, x1, y0, y1};   // k-step 2kb   (k 0..15)
            pa[kb * 2 + 1].u = u32x4{x2, x3, y2, y3};   // k-step 2kb+1 (k 16..31)
        }

        // ---- O += P V (A = P rows q, B = V^T rows d, k-steps of 16)
        __builtin_amdgcn_s_setprio(1);
        #pragma unroll
        for (int ks = 0; ks < 4; ks++) {
            const int ph = ((ks * 2 + hi) ^ c7) * 8;
            bf16x8 vf0 = *(const bf16x8*)&Vs[bb][q32 * 64 + ph];
            bf16x8 vf1 = *(const bf16x8*)&Vs[bb][(32 + q32) * 64 + ph];
            oc0 = __builtin_amdgcn_mfma_f32_32x32x16_bf16(pa[ks].v, vf0, oc0, 0, 0, 0);
            oc1 = __builtin_amdgcn_mfma_f32_32x32x16_bf16(pa[ks].v, vf1, oc1, 0, 0, 0);
        }
        __builtin_amdgcn_s_setprio(0);
        __syncthreads();   // reads of buf bb done; prefetch into bb^1 landed
    }

    // ---- finalize l: q's row-sum is split across lanes q32 and q32+32.
    lsum += __shfl_xor(lsum, 32);
    const float linv = 1.0f / lsum;

    // oc rows are q = (r&3)+8*(r>>2)+4*hi; inv lives at lane q (lo half ok).
    #pragma unroll
    for (int r = 0; r < 16; r++) {
        const int cr = (r & 3) + 8 * (r >> 2) + 4 * hi;
        const float inv = __shfl(linv, cr);
        const int rq = qt * 256 + w * 32 + cr;
        float* o = &Out[((size_t)(b * SS + rq)) * HH + h * HDD + q32];
        o[0]  = oc0[r] * inv;
        o[32] = oc1[r] * inv;
    }
}

// ---------------------------------------------------------------------------
extern "C" void kernel_launch(void* const* d_in, const int* in_sizes, int n_in,
                              void* d_out, int out_size, void* d_ws, size_t ws_size,
                              hipStream_t stream) {
    const float* X  = (const float*)d_in[0];
    const float* Wq = (const float*)d_in[1];
    const float* bq = (const float*)d_in[2];
    const float* Wk = (const float*)d_in[3];
    const float* bk = (const float*)d_in[4];
    const float* Wv = (const float*)d_in[5];
    const float* bv = (const float*)d_in[6];
    float* Out = (float*)d_out;

    const size_t elems = (size_t)BB * SS * HH;  // 8,388,608
    u16* Qw = (u16*)d_ws;                        // Q (pre-scaled) [b,h,s,d]
    u16* Kw = Qw + elems;                        // K [b,h,s,d]
    u16* Vw = Kw + elems;                        // V^T [b,h,d,s]
    // Xb/Wt scratch in d_out (23.1 MB < 33.5 MB; attn fully overwrites).
    u16* Xb = (u16*)d_out;
    u16* Wt = Xb + elems;

    conv<<<dim3(4096 + 3072), 256, 0, stream>>>(X, Wq, Wk, Wv, Xb, Wt);
    qkv_gemm<<<dim3(64, 8, 3), 256, 0, stream>>>(Xb, Wt, bq, bk, bv, Qw, Kw, Vw);
    attn<<<dim3(512), 512, 0, stream>>>(Qw, Kw, Vw, Out);
}

// Round 9
// 231.292 us; speedup vs baseline: 1.2181x; 1.0361x over previous
//
#include <hip/hip_runtime.h>
#include <hip/hip_bf16.h>

// BertSelfAttention (no mask). B=4, S=2048, H=1024, NH=16, HD=64. fp32 I/O.
// Round 15: attn row-sum folded into the MFMA pipe: one extra PV MFMA with
// a ones B-operand accumulates l = sum_k P[k][q] in oc register layout ->
// removes the 30-add lsum tree + all shfl broadcasts from the VALU path.
// qkv (r11: 128x128 2-phase + counted vmcnt(8) + LDS-bounce epilogue) and
// conv unchanged.
#define BB  4
#define SS  2048
#define HH  1024
#define NHH 16
#define HDD 64

typedef unsigned short u16;
typedef unsigned int   u32;
using bf16x8 = __attribute__((ext_vector_type(8))) short;   // 8 bf16 = 4 VGPRs
using f32x4  = __attribute__((ext_vector_type(4))) float;   // MFMA C/D 16x16
using f32x16 = __attribute__((ext_vector_type(16))) float;  // MFMA C/D 32x32
using u32x4  = __attribute__((ext_vector_type(4))) u32;

#define SBAR()   asm volatile("s_barrier" ::: "memory")
#define WAITV0() asm volatile("s_waitcnt vmcnt(0)" ::: "memory")
#define WAITV8() asm volatile("s_waitcnt vmcnt(8)" ::: "memory")
#define LGKM0()  asm volatile("s_waitcnt lgkmcnt(0)" ::: "memory")
#define SCHEDB() __builtin_amdgcn_sched_barrier(0)

// fp32 -> bf16 RNE.
__device__ __forceinline__ u16 f2b(float f) {
    union { float f; u32 u; } x; x.f = f;
    return (u16)((x.u + 0x7fffu + ((x.u >> 16) & 1u)) >> 16);
}

// async 16B global -> LDS (dest = wave-uniform base + lane*16).
__device__ __forceinline__ void gload16(const u16* g, u16* l) {
    __builtin_amdgcn_global_load_lds(
        (const __attribute__((address_space(1))) void*)g,
        (__attribute__((address_space(3))) void*)l, 16, 0, 0);
}

// ---------------------------------------------------------------------------
// conv: fused input conversion.
//   blocks [0,4096):      X fp32 -> bf16 straight copy (8 elems/thread)
//   blocks [4096,7168):   W[k][n] fp32 -> Wt[n][k] bf16 (32x32 transpose)
// ---------------------------------------------------------------------------
__global__ __launch_bounds__(256) void conv(
    const float* __restrict__ X,
    const float* __restrict__ Wq, const float* __restrict__ Wk,
    const float* __restrict__ Wv,
    u16* __restrict__ Xb, u16* __restrict__ Wt)
{
    const int bid = blockIdx.x;
    const int t = threadIdx.x;
    if (bid < 4096) {
        const int i = bid * 256 + t;
        float4 a = ((const float4*)X)[i * 2];
        float4 b = ((const float4*)X)[i * 2 + 1];
        ushort4 s0, s1;
        s0.x = f2b(a.x); s0.y = f2b(a.y); s0.z = f2b(a.z); s0.w = f2b(a.w);
        s1.x = f2b(b.x); s1.y = f2b(b.y); s1.z = f2b(b.z); s1.w = f2b(b.w);
        ((ushort4*)Xb)[i * 2] = s0;
        ((ushort4*)Xb)[i * 2 + 1] = s1;
        return;
    }
    const int idx = bid - 4096;
    const int z = idx >> 10, rem = idx & 1023;
    const int k0 = (rem >> 5) * 32, n0 = (rem & 31) * 32;
    const float* W = (z == 0) ? Wq : (z == 1) ? Wk : Wv;
    u16* out = Wt + (size_t)z * HH * HH;
    __shared__ float T[32][33];
    {
        const int kl = t >> 3, n4 = (t & 7) * 4;
        float4 v = *(const float4*)&W[(size_t)(k0 + kl) * HH + n0 + n4];
        T[n4 + 0][kl] = v.x; T[n4 + 1][kl] = v.y;
        T[n4 + 2][kl] = v.z; T[n4 + 3][kl] = v.w;
    }
    __syncthreads();
    {
        const int nl = t >> 3, k4 = (t & 7) * 4;
        ushort4 s;
        s.x = f2b(T[nl][k4 + 0]); s.y = f2b(T[nl][k4 + 1]);
        s.z = f2b(T[nl][k4 + 2]); s.w = f2b(T[nl][k4 + 3]);
        *(ushort4*)&out[(size_t)(n0 + nl) * HH + k0 + k4] = s;
    }
}

// ---------------------------------------------------------------------------
// qkv_gemm (r11 exact): 128x128 tile, BK=64, global_load_lds + XOR swizzle,
// 4 waves 2x2. Double-buffered LDS + counted vmcnt(8) + raw barriers.
// Epilogue: per-wave 64x64 acc tile -> wave-private LDS bounce ->
// full-128B-line global stores (kills HBM write RMW amplification).
// z<2 (Q,K): operands SWAPPED -> acc = D^T (regs step d) -> [b,h,s,d] rows.
//            Q pre-scaled by 0.125*log2(e).
// z=2 (V):   normal order (regs step s) -> V^T [b,h,d,s] rows.
// ---------------------------------------------------------------------------
__global__ __launch_bounds__(256, 2) void qkv_gemm(
    const u16* __restrict__ Xb, const u16* __restrict__ Wtb,
    const float* __restrict__ bq, const float* __restrict__ bk,
    const float* __restrict__ bv,
    u16* __restrict__ Qw, u16* __restrict__ Kw, u16* __restrict__ Vw)
{
    const int z  = blockIdx.z;
    const float* bias = (z == 0) ? bq : (z == 1) ? bk : bv;
    const int m0 = blockIdx.x * 128, n0 = blockIdx.y * 128;

    __shared__ __align__(16) u16 Xs[2][128 * 64];
    __shared__ __align__(16) u16 Ws[2][128 * 64];

    const int t = threadIdx.x;
    const int w = t >> 6, lane = t & 63, lr = lane & 15, quad = lane >> 4;
    const int l3 = lane >> 3, c7 = lane & 7;
    const int cl = (c7 ^ l3) * 8;          // swizzled source column (u16)
    const int wm = w >> 1, wn = w & 1;

    const u16* Wtz = Wtb + (size_t)z * HH * HH;

    f32x4 acc[4][4];
    #pragma unroll
    for (int i = 0; i < 4; i++)
        #pragma unroll
        for (int j = 0; j < 4; j++) acc[i][j] = f32x4{0.f, 0.f, 0.f, 0.f};

    // prologue: stage tile 0 into buffer 0 (8 gloads per wave).
    #pragma unroll
    for (int e = 0; e < 4; e++) {
        const int r = w * 32 + e * 8 + l3;
        gload16(&Xb [(size_t)(m0 + r) * HH + cl], &Xs[0][(w * 32 + e * 8) * 64]);
        gload16(&Wtz[(size_t)(n0 + r) * HH + cl], &Ws[0][(w * 32 + e * 8) * 64]);
    }

    for (int kt = 0; kt < 16; kt++) {
        const int cur = kt & 1;
        if (kt < 15) {
            const int k0 = (kt + 1) * 64;
            #pragma unroll
            for (int e = 0; e < 4; e++) {
                const int r = w * 32 + e * 8 + l3;
                gload16(&Xb [(size_t)(m0 + r) * HH + k0 + cl],
                        &Xs[cur ^ 1][(w * 32 + e * 8) * 64]);
                gload16(&Wtz[(size_t)(n0 + r) * HH + k0 + cl],
                        &Ws[cur ^ 1][(w * 32 + e * 8) * 64]);
            }
            WAITV8();     // tile kt's 8 loads done; kt+1's 8 stay in flight
        } else {
            WAITV0();
        }
        SBAR();
        SCHEDB();

        #pragma unroll
        for (int kc = 0; kc < 2; kc++) {
            bf16x8 af[4], bfr[4];
            const int ph = ((kc * 4 + quad) ^ c7) * 8;
            #pragma unroll
            for (int mi = 0; mi < 4; mi++)
                af[mi] = *(const bf16x8*)&Xs[cur][(wm * 64 + mi * 16 + lr) * 64 + ph];
            #pragma unroll
            for (int ni = 0; ni < 4; ni++)
                bfr[ni] = *(const bf16x8*)&Ws[cur][(wn * 64 + ni * 16 + lr) * 64 + ph];
            if (z != 2) {   // swapped: acc[mi][ni] = (W.X^T) tile = D^T
                #pragma unroll
                for (int mi = 0; mi < 4; mi++)
                    #pragma unroll
                    for (int ni = 0; ni < 4; ni++)
                        acc[mi][ni] = __builtin_amdgcn_mfma_f32_16x16x32_bf16(
                            bfr[ni], af[mi], acc[mi][ni], 0, 0, 0);
            } else {
                #pragma unroll
                for (int mi = 0; mi < 4; mi++)
                    #pragma unroll
                    for (int ni = 0; ni < 4; ni++)
                        acc[mi][ni] = __builtin_amdgcn_mfma_f32_16x16x32_bf16(
                            af[mi], bfr[ni], acc[mi][ni], 0, 0, 0);
            }
        }
        SCHEDB();
        SBAR();           // all waves done reading buf cur (reused at kt+2)
    }

    // ---- epilogue: LDS bounce -> full-line stores.
    // Wave-private 8KB region in buffer-0 LDS. XOR swizzle byte ^= (row&7)<<4.
    u16* eb = (w < 2 ? &Xs[0][0] : &Ws[0][0]) + (w & 1) * 4096;

    if (z != 2) {
        // acc = D^T: lr = local s, (ni,quad,reg) = d. Dump as [s][d] 64x64.
        const float cs = (z == 0) ? 0.18033688011112042f : 1.0f;
        #pragma unroll
        for (int mi = 0; mi < 4; mi++) {
            const int rr = mi * 16 + lr;
            #pragma unroll
            for (int ni = 0; ni < 4; ni++) {
                const int nb = n0 + wn * 64 + ni * 16 + quad * 4;
                float4 bb4 = *(const float4*)&bias[nb];
                ushort4 vs;
                vs.x = f2b((acc[mi][ni][0] + bb4.x) * cs);
                vs.y = f2b((acc[mi][ni][1] + bb4.y) * cs);
                vs.z = f2b((acc[mi][ni][2] + bb4.z) * cs);
                vs.w = f2b((acc[mi][ni][3] + bb4.w) * cs);
                const int cbyte = (ni * 16 + quad * 4) * 2;
                *(ushort4*)((char*)eb + rr * 128 + (cbyte ^ ((rr & 7) << 4))) = vs;
            }
        }
    } else {
        // acc = D: lr = local d, (mi,quad,reg) = s. Dump as [d][s] 64x64.
        #pragma unroll
        for (int mi = 0; mi < 4; mi++) {
            #pragma unroll
            for (int ni = 0; ni < 4; ni++) {
                const int n = n0 + wn * 64 + ni * 16 + lr;
                const float bv4 = bias[n];
                ushort4 vs;
                vs.x = f2b(acc[mi][ni][0] + bv4);
                vs.y = f2b(acc[mi][ni][1] + bv4);
                vs.z = f2b(acc[mi][ni][2] + bv4);
                vs.w = f2b(acc[mi][ni][3] + bv4);
                const int rr = ni * 16 + lr;
                const int cbyte = (mi * 16 + quad * 4) * 2;
                *(ushort4*)((char*)eb + rr * 128 + (cbyte ^ ((rr & 7) << 4))) = vs;
            }
        }
    }
    LGKM0();
    SCHEDB();

    // read back rows; 8 lanes x 16B = one full 128B output line per row.
    {
        const int rg = lane >> 3;                 // row-in-group 0..7
        const int cb = (lane & 7) * 16;           // byte col 0..112
        const int h = (n0 + wn * 64) >> 6;        // head (64-aligned n-chunk)
        if (z != 2) {
            u16* dst = (z == 0) ? Qw : Kw;
            #pragma unroll
            for (int p = 0; p < 8; p++) {
                const int r2 = p * 8 + rg;        // local s
                bf16x8 rowv = *(const bf16x8*)
                    ((char*)eb + r2 * 128 + (cb ^ ((r2 & 7) << 4)));
                const int sg = m0 + wm * 64 + r2;
                const int b = sg >> 11, s = sg & 2047;
                *(bf16x8*)&dst[((size_t)(b * NHH + h) * SS + s) * HDD + (cb >> 1)]
                    = rowv;
            }
        } else {
            const int mb = m0 + wm * 64;
            const int b = mb >> 11, s0 = mb & 2047;
            #pragma unroll
            for (int p = 0; p < 8; p++) {
                const int r2 = p * 8 + rg;        // local d
                bf16x8 rowv = *(const bf16x8*)
                    ((char*)eb + r2 * 128 + (cb ^ ((r2 & 7) << 4)));
                *(bf16x8*)&Vw[((size_t)(b * NHH + h) * HDD + r2) * SS + s0 + (cb >> 1)]
                    = rowv;
            }
        }
    }
}

// ---------------------------------------------------------------------------
// attn (r7 + MFMA-lsum): flash attention, M=0 softmax (p = exp2(s),
// Q pre-scaled). 512 threads = 8 waves, 32 q-rows/wave -> 256 q/block,
// grid 512. 32x32x16 MFMA, swapped QK^T; P stays in registers
// (cvt_pk + permlane32_swap). Row-sum l computed on the MFMA pipe:
// ol = mfma(pa, ones, ol) -> ol[r] = sum_kv P[kv][q=crow(r,hi)] in oc
// layout (no VALU add tree, no shfl broadcasts).
// ---------------------------------------------------------------------------
__global__ __launch_bounds__(512, 4) void attn(
    const u16* __restrict__ Qb, const u16* __restrict__ Kb,
    const u16* __restrict__ Vtb, float* __restrict__ Out)
{
    // hh = bid&63: all 8 q-blocks of a head land on XCD (hh&7).
    const int bid = blockIdx.x;
    const int hh = bid & 63, qt = bid >> 6;      // qt 0..7
    const int b = hh >> 4, h = hh & 15;
    const size_t hb = (size_t)hh * SS * HDD;

    __shared__ __align__(16) u16 Ks[2][64 * 64];
    __shared__ __align__(16) u16 Vs[2][64 * 64];

    const int t = threadIdx.x;
    const int w = t >> 6, lane = t & 63;
    const int q32 = lane & 31, hi = lane >> 5;
    const int l3 = lane >> 3, c7 = lane & 7;
    const int cl = (c7 ^ l3) * 8;          // swizzled source column (u16)

    // ones B-operand for the row-sum MFMA (bf16 1.0 = 0x3F80).
    bf16x8 vones;
    #pragma unroll
    for (int i = 0; i < 8; i++) vones[i] = (short)0x3F80;

    // Q B-frags (col = q = lane&31, k = d = ds*16 + hi*8 + j), kept in VGPRs.
    bf16x8 qf[4];
    {
        const size_t qrow = (size_t)(qt * 256 + w * 32 + q32);
        #pragma unroll
        for (int ds = 0; ds < 4; ds++)
            qf[ds] = *(const bf16x8*)&Qb[hb + qrow * HDD + ds * 16 + hi * 8];
    }

    // preload tile 0 into buffer 0: wave w stages rows w*8..w*8+7 of K and V^T
    {
        const int r8 = w * 8 + l3;
        gload16(&Kb [hb + (size_t)r8 * HDD + cl], &Ks[0][w * 8 * 64]);
        gload16(&Vtb[hb + (size_t)r8 * SS + cl],  &Vs[0][w * 8 * 64]);
    }
    __syncthreads();

    f32x16 oc0 = {}, oc1 = {};
    f32x16 ol  = {};           // row-sum accumulator (all columns identical)

    for (int kt = 0; kt < SS / 64; kt++) {
        const int bb = kt & 1;
        if (kt + 1 < SS / 64) {   // prefetch next tile into the other buffer
            const int r8 = w * 8 + l3;
            gload16(&Kb [hb + (size_t)((kt + 1) * 64 + r8) * HDD + cl],
                    &Ks[bb ^ 1][w * 8 * 64]);
            gload16(&Vtb[hb + (size_t)r8 * SS + (kt + 1) * 64 + cl],
                    &Vs[bb ^ 1][w * 8 * 64]);
        }

        // ---- S^T = K Q^T: two 32x32 tiles (k-rows 0..31, 32..63), q=lane&31
        f32x16 sc0 = {}, sc1 = {};
        __builtin_amdgcn_s_setprio(1);
        #pragma unroll
        for (int ds = 0; ds < 4; ds++) {
            const int ph = ((ds * 2 + hi) ^ c7) * 8;
            bf16x8 kf0 = *(const bf16x8*)&Ks[bb][q32 * 64 + ph];
            bf16x8 kf1 = *(const bf16x8*)&Ks[bb][(32 + q32) * 64 + ph];
            sc0 = __builtin_amdgcn_mfma_f32_32x32x16_bf16(kf0, qf[ds], sc0, 0, 0, 0);
            sc1 = __builtin_amdgcn_mfma_f32_32x32x16_bf16(kf1, qf[ds], sc1, 0, 0, 0);
        }
        __builtin_amdgcn_s_setprio(0);

        // ---- p = exp2(s); in-register pack to PV A-frags via cvt_pk+permlane.
        // lane owns P[k = kb*32 + (r&3)+8*(r>>2)+4*hi][q = q32].
        union PU { u32x4 u; bf16x8 v; } pa[4];
        #pragma unroll
        for (int kb = 0; kb < 2; kb++) {
            const f32x16 s = kb ? sc1 : sc0;
            float p[16];
            #pragma unroll
            for (int r = 0; r < 16; r++) p[r] = __builtin_amdgcn_exp2f(s[r]);
            u32 x0, x1, x2, x3, y0, y1, y2, y3;
            asm("v_cvt_pk_bf16_f32 %0, %1, %2" : "=v"(x0) : "v"(p[0]),  "v"(p[1]));
            asm("v_cvt_pk_bf16_f32 %0, %1, %2" : "=v"(x1) : "v"(p[2]),  "v"(p[3]));
            asm("v_cvt_pk_bf16_f32 %0, %1, %2" : "=v"(y0) : "v"(p[4]),  "v"(p[5]));
            asm("v_cvt_pk_bf16_f32 %0, %1, %2" : "=v"(y1) : "v"(p[6]),  "v"(p[7]));
            asm("v_cvt_pk_bf16_f32 %0, %1, %2" : "=v"(x2) : "v"(p[8]),  "v"(p[9]));
            asm("v_cvt_pk_bf16_f32 %0, %1, %2" : "=v"(x3) : "v"(p[10]), "v"(p[11]));
            asm("v_cvt_pk_bf16_f32 %0, %1, %2" : "=v"(y2) : "v"(p[12]), "v"(p[13]));
            asm("v_cvt_pk_bf16_f32 %0, %1, %2" : "=v"(y3) : "v"(p[14]), "v"(p[15]));
            // swap hi-half(x) <-> lo-half(y): x' = frag reg{0,1}, y' = reg{2,3}
            asm("v_permlane32_swap_b32 %0, %1" : "+v"(x0), "+v"(y0));
            asm("v_permlane32_swap_b32 %0, %1" : "+v"(x1), "+v"(y1));
            asm("v_permlane32_swap_b32 %0, %1" : "+v"(x2), "+v"(y2));
            asm("v_permlane32_swap_b32 %0, %1" : "+v"(x3), "+v"(y3));
            pa[kb * 2 + 0].u = u32x4{x0, x1, y0, y1};   // k-step 2kb   (k 0..15)
            pa[kb * 2 + 1].u = u32x4{x2, x3, y2, y3};   // k-step 2kb+1 (k 16..31)
        }

        // ---- O += P V (A = P rows q, B = V^T rows d, k-steps of 16);
        //      l += P . 1 on the same pipe.
        __builtin_amdgcn_s_setprio(1);
        #pragma unroll
        for (int ks = 0; ks < 4; ks++) {
            const int ph = ((ks * 2 + hi) ^ c7) * 8;
            bf16x8 vf0 = *(const bf16x8*)&Vs[bb][q32 * 64 + ph];
            bf16x8 vf1 = *(const bf16x8*)&Vs[bb][(32 + q32) * 64 + ph];
            oc0 = __builtin_amdgcn_mfma_f32_32x32x16_bf16(pa[ks].v, vf0, oc0, 0, 0, 0);
            oc1 = __builtin_amdgcn_mfma_f32_32x32x16_bf16(pa[ks].v, vf1, oc1, 0, 0, 0);
            ol  = __builtin_amdgcn_mfma_f32_32x32x16_bf16(pa[ks].v, vones, ol, 0, 0, 0);
        }
        __builtin_amdgcn_s_setprio(0);
        __syncthreads();   // reads of buf bb done; prefetch into bb^1 landed
    }

    // ---- finalize: ol[r] = full row-sum for q = crow(r,hi) (same value in
    // every lane's column) — divide directly, no shuffles needed.
    #pragma unroll
    for (int r = 0; r < 16; r++) {
        const float inv = 1.0f / ol[r];
        const int cr = (r & 3) + 8 * (r >> 2) + 4 * hi;
        const int rq = qt * 256 + w * 32 + cr;
        float* o = &Out[((size_t)(b * SS + rq)) * HH + h * HDD + q32];
        o[0]  = oc0[r] * inv;
        o[32] = oc1[r] * inv;
    }
}

// ---------------------------------------------------------------------------
extern "C" void kernel_launch(void* const* d_in, const int* in_sizes, int n_in,
                              void* d_out, int out_size, void* d_ws, size_t ws_size,
                              hipStream_t stream) {
    const float* X  = (const float*)d_in[0];
    const float* Wq = (const float*)d_in[1];
    const float* bq = (const float*)d_in[2];
    const float* Wk = (const float*)d_in[3];
    const float* bk = (const float*)d_in[4];
    const float* Wv = (const float*)d_in[5];
    const float* bv = (const float*)d_in[6];
    float* Out = (float*)d_out;

    const size_t elems = (size_t)BB * SS * HH;  // 8,388,608
    u16* Qw = (u16*)d_ws;                        // Q (pre-scaled) [b,h,s,d]
    u16* Kw = Qw + elems;                        // K [b,h,s,d]
    u16* Vw = Kw + elems;                        // V^T [b,h,d,s]
    // Xb/Wt scratch in d_out (23.1 MB < 33.5 MB; attn fully overwrites).
    u16* Xb = (u16*)d_out;
    u16* Wt = Xb + elems;

    conv<<<dim3(4096 + 3072), 256, 0, stream>>>(X, Wq, Wk, Wv, Xb, Wt);
    qkv_gemm<<<dim3(64, 8, 3), 256, 0, stream>>>(Xb, Wt, bq, bk, bv, Qw, Kw, Vw);
    attn<<<dim3(512), 512, 0, stream>>>(Qw, Kw, Vw, Out);
}

// Round 10
// 227.302 us; speedup vs baseline: 1.2395x; 1.0176x over previous
//
#include <hip/hip_runtime.h>
#include <hip/hip_bf16.h>

// BertSelfAttention (no mask). B=4, S=2048, H=1024, NH=16, HD=64. fp32 I/O.
// Round 16: qkv_gemm grid flattened to 1-D with an XCD-locality remap:
// XCD c (= bid&7) owns X m-panels {c, c+8, ..., c+56} across all (y,z), so
// the 24x-reused X panels (256KB each) stay in that XCD's 4MB L2 -> gload
// stalls become L2 hits (2 waves/SIMD can hide 200cyc, not 900cyc).
// attn = r15 (82.5us: MFMA-folded row-sum). conv unchanged.
#define BB  4
#define SS  2048
#define HH  1024
#define NHH 16
#define HDD 64

typedef unsigned short u16;
typedef unsigned int   u32;
using bf16x8 = __attribute__((ext_vector_type(8))) short;   // 8 bf16 = 4 VGPRs
using f32x4  = __attribute__((ext_vector_type(4))) float;   // MFMA C/D 16x16
using f32x16 = __attribute__((ext_vector_type(16))) float;  // MFMA C/D 32x32
using u32x4  = __attribute__((ext_vector_type(4))) u32;

#define SBAR()   asm volatile("s_barrier" ::: "memory")
#define WAITV0() asm volatile("s_waitcnt vmcnt(0)" ::: "memory")
#define WAITV8() asm volatile("s_waitcnt vmcnt(8)" ::: "memory")
#define LGKM0()  asm volatile("s_waitcnt lgkmcnt(0)" ::: "memory")
#define SCHEDB() __builtin_amdgcn_sched_barrier(0)

// fp32 -> bf16 RNE.
__device__ __forceinline__ u16 f2b(float f) {
    union { float f; u32 u; } x; x.f = f;
    return (u16)((x.u + 0x7fffu + ((x.u >> 16) & 1u)) >> 16);
}

// async 16B global -> LDS (dest = wave-uniform base + lane*16).
__device__ __forceinline__ void gload16(const u16* g, u16* l) {
    __builtin_amdgcn_global_load_lds(
        (const __attribute__((address_space(1))) void*)g,
        (__attribute__((address_space(3))) void*)l, 16, 0, 0);
}

// ---------------------------------------------------------------------------
// conv: fused input conversion.
//   blocks [0,4096):      X fp32 -> bf16 straight copy (8 elems/thread)
//   blocks [4096,7168):   W[k][n] fp32 -> Wt[n][k] bf16 (32x32 transpose)
// ---------------------------------------------------------------------------
__global__ __launch_bounds__(256) void conv(
    const float* __restrict__ X,
    const float* __restrict__ Wq, const float* __restrict__ Wk,
    const float* __restrict__ Wv,
    u16* __restrict__ Xb, u16* __restrict__ Wt)
{
    const int bid = blockIdx.x;
    const int t = threadIdx.x;
    if (bid < 4096) {
        const int i = bid * 256 + t;
        float4 a = ((const float4*)X)[i * 2];
        float4 b = ((const float4*)X)[i * 2 + 1];
        ushort4 s0, s1;
        s0.x = f2b(a.x); s0.y = f2b(a.y); s0.z = f2b(a.z); s0.w = f2b(a.w);
        s1.x = f2b(b.x); s1.y = f2b(b.y); s1.z = f2b(b.z); s1.w = f2b(b.w);
        ((ushort4*)Xb)[i * 2] = s0;
        ((ushort4*)Xb)[i * 2 + 1] = s1;
        return;
    }
    const int idx = bid - 4096;
    const int z = idx >> 10, rem = idx & 1023;
    const int k0 = (rem >> 5) * 32, n0 = (rem & 31) * 32;
    const float* W = (z == 0) ? Wq : (z == 1) ? Wk : Wv;
    u16* out = Wt + (size_t)z * HH * HH;
    __shared__ float T[32][33];
    {
        const int kl = t >> 3, n4 = (t & 7) * 4;
        float4 v = *(const float4*)&W[(size_t)(k0 + kl) * HH + n0 + n4];
        T[n4 + 0][kl] = v.x; T[n4 + 1][kl] = v.y;
        T[n4 + 2][kl] = v.z; T[n4 + 3][kl] = v.w;
    }
    __syncthreads();
    {
        const int nl = t >> 3, k4 = (t & 7) * 4;
        ushort4 s;
        s.x = f2b(T[nl][k4 + 0]); s.y = f2b(T[nl][k4 + 1]);
        s.z = f2b(T[nl][k4 + 2]); s.w = f2b(T[nl][k4 + 3]);
        *(ushort4*)&out[(size_t)(n0 + nl) * HH + k0 + k4] = s;
    }
}

// ---------------------------------------------------------------------------
// qkv_gemm (r11 structure + XCD remap): 128x128 tile, BK=64,
// global_load_lds + XOR swizzle, 4 waves 2x2. Double-buffered LDS +
// counted vmcnt(8) + raw barriers. Epilogue: per-wave 64x64 acc tile ->
// wave-private LDS bounce -> full-128B-line global stores.
// 1-D grid 1536; remap: x = (bid&7) + 8*((bid>>3)&7), yz = bid>>6,
// y = yz&7, z = yz>>3 -> XCD (bid&7) owns 8 x-panels for all (y,z).
// z<2 (Q,K): operands SWAPPED -> acc = D^T (regs step d) -> [b,h,s,d] rows.
//            Q pre-scaled by 0.125*log2(e).
// z=2 (V):   normal order (regs step s) -> V^T [b,h,d,s] rows.
// ---------------------------------------------------------------------------
__global__ __launch_bounds__(256, 2) void qkv_gemm(
    const u16* __restrict__ Xb, const u16* __restrict__ Wtb,
    const float* __restrict__ bq, const float* __restrict__ bk,
    const float* __restrict__ bv,
    u16* __restrict__ Qw, u16* __restrict__ Kw, u16* __restrict__ Vw)
{
    // XCD-locality remap (bijective on 1536 = 64 x * 8 y * 3 z).
    const int bid = blockIdx.x;
    const int bx = (bid & 7) + 8 * ((bid >> 3) & 7);
    const int yz = bid >> 6;
    const int by = yz & 7;
    const int z  = yz >> 3;

    const float* bias = (z == 0) ? bq : (z == 1) ? bk : bv;
    const int m0 = bx * 128, n0 = by * 128;

    __shared__ __align__(16) u16 Xs[2][128 * 64];
    __shared__ __align__(16) u16 Ws[2][128 * 64];

    const int t = threadIdx.x;
    const int w = t >> 6, lane = t & 63, lr = lane & 15, quad = lane >> 4;
    const int l3 = lane >> 3, c7 = lane & 7;
    const int cl = (c7 ^ l3) * 8;          // swizzled source column (u16)
    const int wm = w >> 1, wn = w & 1;

    const u16* Wtz = Wtb + (size_t)z * HH * HH;

    f32x4 acc[4][4];
    #pragma unroll
    for (int i = 0; i < 4; i++)
        #pragma unroll
        for (int j = 0; j < 4; j++) acc[i][j] = f32x4{0.f, 0.f, 0.f, 0.f};

    // prologue: stage tile 0 into buffer 0 (8 gloads per wave).
    #pragma unroll
    for (int e = 0; e < 4; e++) {
        const int r = w * 32 + e * 8 + l3;
        gload16(&Xb [(size_t)(m0 + r) * HH + cl], &Xs[0][(w * 32 + e * 8) * 64]);
        gload16(&Wtz[(size_t)(n0 + r) * HH + cl], &Ws[0][(w * 32 + e * 8) * 64]);
    }

    for (int kt = 0; kt < 16; kt++) {
        const int cur = kt & 1;
        if (kt < 15) {
            const int k0 = (kt + 1) * 64;
            #pragma unroll
            for (int e = 0; e < 4; e++) {
                const int r = w * 32 + e * 8 + l3;
                gload16(&Xb [(size_t)(m0 + r) * HH + k0 + cl],
                        &Xs[cur ^ 1][(w * 32 + e * 8) * 64]);
                gload16(&Wtz[(size_t)(n0 + r) * HH + k0 + cl],
                        &Ws[cur ^ 1][(w * 32 + e * 8) * 64]);
            }
            WAITV8();     // tile kt's 8 loads done; kt+1's 8 stay in flight
        } else {
            WAITV0();
        }
        SBAR();
        SCHEDB();

        #pragma unroll
        for (int kc = 0; kc < 2; kc++) {
            bf16x8 af[4], bfr[4];
            const int ph = ((kc * 4 + quad) ^ c7) * 8;
            #pragma unroll
            for (int mi = 0; mi < 4; mi++)
                af[mi] = *(const bf16x8*)&Xs[cur][(wm * 64 + mi * 16 + lr) * 64 + ph];
            #pragma unroll
            for (int ni = 0; ni < 4; ni++)
                bfr[ni] = *(const bf16x8*)&Ws[cur][(wn * 64 + ni * 16 + lr) * 64 + ph];
            if (z != 2) {   // swapped: acc[mi][ni] = (W.X^T) tile = D^T
                #pragma unroll
                for (int mi = 0; mi < 4; mi++)
                    #pragma unroll
                    for (int ni = 0; ni < 4; ni++)
                        acc[mi][ni] = __builtin_amdgcn_mfma_f32_16x16x32_bf16(
                            bfr[ni], af[mi], acc[mi][ni], 0, 0, 0);
            } else {
                #pragma unroll
                for (int mi = 0; mi < 4; mi++)
                    #pragma unroll
                    for (int ni = 0; ni < 4; ni++)
                        acc[mi][ni] = __builtin_amdgcn_mfma_f32_16x16x32_bf16(
                            af[mi], bfr[ni], acc[mi][ni], 0, 0, 0);
            }
        }
        SCHEDB();
        SBAR();           // all waves done reading buf cur (reused at kt+2)
    }

    // ---- epilogue: LDS bounce -> full-line stores.
    // Wave-private 8KB region in buffer-0 LDS. XOR swizzle byte ^= (row&7)<<4.
    u16* eb = (w < 2 ? &Xs[0][0] : &Ws[0][0]) + (w & 1) * 4096;

    if (z != 2) {
        // acc = D^T: lr = local s, (ni,quad,reg) = d. Dump as [s][d] 64x64.
        const float cs = (z == 0) ? 0.18033688011112042f : 1.0f;
        #pragma unroll
        for (int mi = 0; mi < 4; mi++) {
            const int rr = mi * 16 + lr;
            #pragma unroll
            for (int ni = 0; ni < 4; ni++) {
                const int nb = n0 + wn * 64 + ni * 16 + quad * 4;
                float4 bb4 = *(const float4*)&bias[nb];
                ushort4 vs;
                vs.x = f2b((acc[mi][ni][0] + bb4.x) * cs);
                vs.y = f2b((acc[mi][ni][1] + bb4.y) * cs);
                vs.z = f2b((acc[mi][ni][2] + bb4.z) * cs);
                vs.w = f2b((acc[mi][ni][3] + bb4.w) * cs);
                const int cbyte = (ni * 16 + quad * 4) * 2;
                *(ushort4*)((char*)eb + rr * 128 + (cbyte ^ ((rr & 7) << 4))) = vs;
            }
        }
    } else {
        // acc = D: lr = local d, (mi,quad,reg) = s. Dump as [d][s] 64x64.
        #pragma unroll
        for (int mi = 0; mi < 4; mi++) {
            #pragma unroll
            for (int ni = 0; ni < 4; ni++) {
                const int n = n0 + wn * 64 + ni * 16 + lr;
                const float bv4 = bias[n];
                ushort4 vs;
                vs.x = f2b(acc[mi][ni][0] + bv4);
                vs.y = f2b(acc[mi][ni][1] + bv4);
                vs.z = f2b(acc[mi][ni][2] + bv4);
                vs.w = f2b(acc[mi][ni][3] + bv4);
                const int rr = ni * 16 + lr;
                const int cbyte = (mi * 16 + quad * 4) * 2;
                *(ushort4*)((char*)eb + rr * 128 + (cbyte ^ ((rr & 7) << 4))) = vs;
            }
        }
    }
    LGKM0();
    SCHEDB();

    // read back rows; 8 lanes x 16B = one full 128B output line per row.
    {
        const int rg = lane >> 3;                 // row-in-group 0..7
        const int cb = (lane & 7) * 16;           // byte col 0..112
        const int h = (n0 + wn * 64) >> 6;        // head (64-aligned n-chunk)
        if (z != 2) {
            u16* dst = (z == 0) ? Qw : Kw;
            #pragma unroll
            for (int p = 0; p < 8; p++) {
                const int r2 = p * 8 + rg;        // local s
                bf16x8 rowv = *(const bf16x8*)
                    ((char*)eb + r2 * 128 + (cb ^ ((r2 & 7) << 4)));
                const int sg = m0 + wm * 64 + r2;
                const int b = sg >> 11, s = sg & 2047;
                *(bf16x8*)&dst[((size_t)(b * NHH + h) * SS + s) * HDD + (cb >> 1)]
                    = rowv;
            }
        } else {
            const int mb = m0 + wm * 64;
            const int b = mb >> 11, s0 = mb & 2047;
            #pragma unroll
            for (int p = 0; p < 8; p++) {
                const int r2 = p * 8 + rg;        // local d
                bf16x8 rowv = *(const bf16x8*)
                    ((char*)eb + r2 * 128 + (cb ^ ((r2 & 7) << 4)));
                *(bf16x8*)&Vw[((size_t)(b * NHH + h) * HDD + r2) * SS + s0 + (cb >> 1)]
                    = rowv;
            }
        }
    }
}

// ---------------------------------------------------------------------------
// attn (r15): flash attention, M=0 softmax (p = exp2(s), Q pre-scaled).
// 512 threads = 8 waves, 32 q-rows/wave -> 256 q/block, grid 512.
// 32x32x16 MFMA, swapped QK^T; P stays in registers (cvt_pk +
// permlane32_swap). Row-sum l on the MFMA pipe: ol = mfma(pa, ones, ol).
// ---------------------------------------------------------------------------
__global__ __launch_bounds__(512, 4) void attn(
    const u16* __restrict__ Qb, const u16* __restrict__ Kb,
    const u16* __restrict__ Vtb, float* __restrict__ Out)
{
    // hh = bid&63: all 8 q-blocks of a head land on XCD (hh&7).
    const int bid = blockIdx.x;
    const int hh = bid & 63, qt = bid >> 6;      // qt 0..7
    const int b = hh >> 4, h = hh & 15;
    const size_t hb = (size_t)hh * SS * HDD;

    __shared__ __align__(16) u16 Ks[2][64 * 64];
    __shared__ __align__(16) u16 Vs[2][64 * 64];

    const int t = threadIdx.x;
    const int w = t >> 6, lane = t & 63;
    const int q32 = lane & 31, hi = lane >> 5;
    const int l3 = lane >> 3, c7 = lane & 7;
    const int cl = (c7 ^ l3) * 8;          // swizzled source column (u16)

    // ones B-operand for the row-sum MFMA (bf16 1.0 = 0x3F80).
    bf16x8 vones;
    #pragma unroll
    for (int i = 0; i < 8; i++) vones[i] = (short)0x3F80;

    // Q B-frags (col = q = lane&31, k = d = ds*16 + hi*8 + j), kept in VGPRs.
    bf16x8 qf[4];
    {
        const size_t qrow = (size_t)(qt * 256 + w * 32 + q32);
        #pragma unroll
        for (int ds = 0; ds < 4; ds++)
            qf[ds] = *(const bf16x8*)&Qb[hb + qrow * HDD + ds * 16 + hi * 8];
    }

    // preload tile 0 into buffer 0: wave w stages rows w*8..w*8+7 of K and V^T
    {
        const int r8 = w * 8 + l3;
        gload16(&Kb [hb + (size_t)r8 * HDD + cl], &Ks[0][w * 8 * 64]);
        gload16(&Vtb[hb + (size_t)r8 * SS + cl],  &Vs[0][w * 8 * 64]);
    }
    __syncthreads();

    f32x16 oc0 = {}, oc1 = {};
    f32x16 ol  = {};           // row-sum accumulator (all columns identical)

    for (int kt = 0; kt < SS / 64; kt++) {
        const int bb = kt & 1;
        if (kt + 1 < SS / 64) {   // prefetch next tile into the other buffer
            const int r8 = w * 8 + l3;
            gload16(&Kb [hb + (size_t)((kt + 1) * 64 + r8) * HDD + cl],
                    &Ks[bb ^ 1][w * 8 * 64]);
            gload16(&Vtb[hb + (size_t)r8 * SS + (kt + 1) * 64 + cl],
                    &Vs[bb ^ 1][w * 8 * 64]);
        }

        // ---- S^T = K Q^T: two 32x32 tiles (k-rows 0..31, 32..63), q=lane&31
        f32x16 sc0 = {}, sc1 = {};
        __builtin_amdgcn_s_setprio(1);
        #pragma unroll
        for (int ds = 0; ds < 4; ds++) {
            const int ph = ((ds * 2 + hi) ^ c7) * 8;
            bf16x8 kf0 = *(const bf16x8*)&Ks[bb][q32 * 64 + ph];
            bf16x8 kf1 = *(const bf16x8*)&Ks[bb][(32 + q32) * 64 + ph];
            sc0 = __builtin_amdgcn_mfma_f32_32x32x16_bf16(kf0, qf[ds], sc0, 0, 0, 0);
            sc1 = __builtin_amdgcn_mfma_f32_32x32x16_bf16(kf1, qf[ds], sc1, 0, 0, 0);
        }
        __builtin_amdgcn_s_setprio(0);

        // ---- p = exp2(s); in-register pack to PV A-frags via cvt_pk+permlane.
        // lane owns P[k = kb*32 + (r&3)+8*(r>>2)+4*hi][q = q32].
        union PU { u32x4 u; bf16x8 v; } pa[4];
        #pragma unroll
        for (int kb = 0; kb < 2; kb++) {
            const f32x16 s = kb ? sc1 : sc0;
            float p[16];
            #pragma unroll
            for (int r = 0; r < 16; r++) p[r] = __builtin_amdgcn_exp2f(s[r]);
            u32 x0, x1, x2, x3, y0, y1, y2, y3;
            asm("v_cvt_pk_bf16_f32 %0, %1, %2" : "=v"(x0) : "v"(p[0]),  "v"(p[1]));
            asm("v_cvt_pk_bf16_f32 %0, %1, %2" : "=v"(x1) : "v"(p[2]),  "v"(p[3]));
            asm("v_cvt_pk_bf16_f32 %0, %1, %2" : "=v"(y0) : "v"(p[4]),  "v"(p[5]));
            asm("v_cvt_pk_bf16_f32 %0, %1, %2" : "=v"(y1) : "v"(p[6]),  "v"(p[7]));
            asm("v_cvt_pk_bf16_f32 %0, %1, %2" : "=v"(x2) : "v"(p[8]),  "v"(p[9]));
            asm("v_cvt_pk_bf16_f32 %0, %1, %2" : "=v"(x3) : "v"(p[10]), "v"(p[11]));
            asm("v_cvt_pk_bf16_f32 %0, %1, %2" : "=v"(y2) : "v"(p[12]), "v"(p[13]));
            asm("v_cvt_pk_bf16_f32 %0, %1, %2" : "=v"(y3) : "v"(p[14]), "v"(p[15]));
            // swap hi-half(x) <-> lo-half(y): x' = frag reg{0,1}, y' = reg{2,3}
            asm("v_permlane32_swap_b32 %0, %1" : "+v"(x0), "+v"(y0));
            asm("v_permlane32_swap_b32 %0, %1" : "+v"(x1), "+v"(y1));
            asm("v_permlane32_swap_b32 %0, %1" : "+v"(x2), "+v"(y2));
            asm("v_permlane32_swap_b32 %0, %1" : "+v"(x3), "+v"(y3));
            pa[kb * 2 + 0].u = u32x4{x0, x1, y0, y1};   // k-step 2kb   (k 0..15)
            pa[kb * 2 + 1].u = u32x4{x2, x3, y2, y3};   // k-step 2kb+1 (k 16..31)
        }

        // ---- O += P V (A = P rows q, B = V^T rows d, k-steps of 16);
        //      l += P . 1 on the same pipe.
        __builtin_amdgcn_s_setprio(1);
        #pragma unroll
        for (int ks = 0; ks < 4; ks++) {
            const int ph = ((ks * 2 + hi) ^ c7) * 8;
            bf16x8 vf0 = *(const bf16x8*)&Vs[bb][q32 * 64 + ph];
            bf16x8 vf1 = *(const bf16x8*)&Vs[bb][(32 + q32) * 64 + ph];
            oc0 = __builtin_amdgcn_mfma_f32_32x32x16_bf16(pa[ks].v, vf0, oc0, 0, 0, 0);
            oc1 = __builtin_amdgcn_mfma_f32_32x32x16_bf16(pa[ks].v, vf1, oc1, 0, 0, 0);
            ol  = __builtin_amdgcn_mfma_f32_32x32x16_bf16(pa[ks].v, vones, ol, 0, 0, 0);
        }
        __builtin_amdgcn_s_setprio(0);
        __syncthreads();   // reads of buf bb done; prefetch into bb^1 landed
    }

    // ---- finalize: ol[r] = full row-sum for q = crow(r,hi) (same value in
    // every lane's column) — divide directly, no shuffles needed.
    #pragma unroll
    for (int r = 0; r < 16; r++) {
        const float inv = 1.0f / ol[r];
        const int cr = (r & 3) + 8 * (r >> 2) + 4 * hi;
        const int rq = qt * 256 + w * 32 + cr;
        float* o = &Out[((size_t)(b * SS + rq)) * HH + h * HDD + q32];
        o[0]  = oc0[r] * inv;
        o[32] = oc1[r] * inv;
    }
}

// ---------------------------------------------------------------------------
extern "C" void kernel_launch(void* const* d_in, const int* in_sizes, int n_in,
                              void* d_out, int out_size, void* d_ws, size_t ws_size,
                              hipStream_t stream) {
    const float* X  = (const float*)d_in[0];
    const float* Wq = (const float*)d_in[1];
    const float* bq = (const float*)d_in[2];
    const float* Wk = (const float*)d_in[3];
    const float* bk = (const float*)d_in[4];
    const float* Wv = (const float*)d_in[5];
    const float* bv = (const float*)d_in[6];
    float* Out = (float*)d_out;

    const size_t elems = (size_t)BB * SS * HH;  // 8,388,608
    u16* Qw = (u16*)d_ws;                        // Q (pre-scaled) [b,h,s,d]
    u16* Kw = Qw + elems;                        // K [b,h,s,d]
    u16* Vw = Kw + elems;                        // V^T [b,h,d,s]
    // Xb/Wt scratch in d_out (23.1 MB < 33.5 MB; attn fully overwrites).
    u16* Xb = (u16*)d_out;
    u16* Wt = Xb + elems;

    conv<<<dim3(4096 + 3072), 256, 0, stream>>>(X, Wq, Wk, Wv, Xb, Wt);
    qkv_gemm<<<dim3(1536), 256, 0, stream>>>(Xb, Wt, bq, bk, bv, Qw, Kw, Vw);
    attn<<<dim3(512), 512, 0, stream>>>(Qw, Kw, Vw, Out);
}